// Round 2
// baseline (175.302 us; speedup 1.0000x reference)
//
#include <hip/hip_runtime.h>
#include <hip/hip_bf16.h>

#define B_   8
#define TQ_  100
#define TS_  100
#define E_   512
#define D_   512
#define K_   1024
#define M_   (B_*TQ_*TS_)   // 80000

#define MT   128            // M-tile per block
#define NT   256            // N-tile per block (2 blocks cover D=512)
#define BK   64             // K per staged step
#define NTHREADS 512        // 8 waves (2M x 4N)

typedef __attribute__((ext_vector_type(4))) float f32x4;
typedef __attribute__((ext_vector_type(8))) short bf16x8;

__device__ __forceinline__ short f2bf(float f) {
  __hip_bfloat16 h = __float2bfloat16(f);
  return *reinterpret_cast<short*>(&h);
}

__device__ __forceinline__ float fast_tanh(float x) {
  float e = __expf(2.0f * x);
  return 1.0f - 2.0f / (e + 1.0f);
}

__device__ __forceinline__ void gld16(const void* g, void* l) {
  __builtin_amdgcn_global_load_lds(
      (const __attribute__((address_space(1))) unsigned int*)g,
      (__attribute__((address_space(3))) unsigned int*)l, 16, 0, 0);
}

// ---- prep: W1 [K=1024][D=512] f32 -> W1sw bf16 [n=512][k=1024], XOR-preswizzled
// so that a LINEAR global_load_lds of any 128B row-segment lands such that the
// ds_read at (n*128 + (kb ^ ((n&7)<<4))) returns element k = k0 + kb/2.
__global__ void prep_w1(const float* __restrict__ W1, short* __restrict__ W1sw) {
  int idx = blockIdx.x * 256 + threadIdx.x;   // over K_*D_
  int k = idx >> 9;          // /512
  int n = idx & (D_ - 1);
  int byte = (k * 2) ^ ((n & 7) << 4);        // XOR stays within 128B segment
  W1sw[(size_t)n * K_ + (byte >> 1)] = f2bf(W1[idx]);
}

// ---- kernel 1: partial scores over n in [bn*256, bn*256+256) ----
__launch_bounds__(NTHREADS, 4)
__global__ void scores_kernel(const float* __restrict__ src,
                              const float* __restrict__ tgt,
                              const short* __restrict__ W1sw,
                              const float* __restrict__ b1,
                              const float* __restrict__ w2,
                              float* __restrict__ sc0,
                              float* __restrict__ sc1) {
  __shared__ __align__(16) char Alds[MT * 128];        // 16 KB, single-buffered
  __shared__ __align__(16) char Blds[2][NT * 128];     // 2 x 32 KB, double-buffered

  const int tid  = threadIdx.x;
  const int wave = tid >> 6;
  const int lane = tid & 63;
  const int lr   = lane & 15;      // fragment row/col
  const int lg   = lane >> 4;      // k-octet group
  const int wr   = wave >> 2;      // wave M index (0..1)
  const int wc   = wave & 3;       // wave N index (0..3)
  const int bm   = blockIdx.x >> 1;
  const int bn   = blockIdx.x & 1;
  const int m0   = bm * MT;
  const int n0   = bn * NT;

  f32x4 acc[4][4];
  #pragma unroll
  for (int i = 0; i < 4; i++)
    #pragma unroll
    for (int j = 0; j < 4; j++)
      acc[i][j] = (f32x4){0.f, 0.f, 0.f, 0.f};

  // A-stage mapping: thread -> (row, 16 consecutive k)
  const int ra = tid >> 2;            // 0..127
  const int ka = (tid & 3) * 16;      // k offset within BK: 0,16,32,48
  const int swA = (ra & 7) << 4;
  // B-stage lane mapping for gld16 (linear LDS: base + lane*16)
  const int bl_row = lane >> 3;       // +row within 8-row group
  const int bl_in  = (lane & 7) * 16; // byte within 128B row

  // ---- prologue: stage B[0], A[0] ----
  #pragma unroll
  for (int j = 0; j < 4; j++) {
    int nl = wave * 32 + j * 8 + bl_row;
    const char* gp = (const char*)W1sw + (size_t)(n0 + nl) * 2048 + bl_in;
    gld16(gp, Blds[0] + wave * 4096 + j * 1024);
  }
  {
    const float* Ap = src + (size_t)(m0 + ra) * E_ + ka;
    f32x4 r0 = *reinterpret_cast<const f32x4*>(Ap);
    f32x4 r1 = *reinterpret_cast<const f32x4*>(Ap + 4);
    f32x4 r2 = *reinterpret_cast<const f32x4*>(Ap + 8);
    f32x4 r3 = *reinterpret_cast<const f32x4*>(Ap + 12);
    bf16x8 w0, w1;
    w0[0]=f2bf(r0[0]); w0[1]=f2bf(r0[1]); w0[2]=f2bf(r0[2]); w0[3]=f2bf(r0[3]);
    w0[4]=f2bf(r1[0]); w0[5]=f2bf(r1[1]); w0[6]=f2bf(r1[2]); w0[7]=f2bf(r1[3]);
    w1[0]=f2bf(r2[0]); w1[1]=f2bf(r2[1]); w1[2]=f2bf(r2[2]); w1[3]=f2bf(r2[3]);
    w1[4]=f2bf(r3[0]); w1[5]=f2bf(r3[1]); w1[6]=f2bf(r3[2]); w1[7]=f2bf(r3[3]);
    int kb = ka * 2;
    *reinterpret_cast<bf16x8*>(Alds + ra * 128 + ( kb       ^ swA)) = w0;
    *reinterpret_cast<bf16x8*>(Alds + ra * 128 + ((kb + 16) ^ swA)) = w1;
  }
  __syncthreads();   // drains vmcnt(0): B[0] in LDS; A[0] written

  int cur = 0;
  for (int t = 0; t < 16; ++t) {
    const int k0n = (t + 1) * BK;
    const bool pf = (t < 15);
    f32x4 r0, r1, r2, r3;
    if (pf) {
      // issue A[t+1] (longest latency) then B[t+1] BEFORE this step's MFMA
      const float* Ap = ((k0n < E_) ? src : tgt)
                        + (size_t)(m0 + ra) * E_ + (k0n & (E_ - 1)) + ka;
      r0 = *reinterpret_cast<const f32x4*>(Ap);
      r1 = *reinterpret_cast<const f32x4*>(Ap + 4);
      r2 = *reinterpret_cast<const f32x4*>(Ap + 8);
      r3 = *reinterpret_cast<const f32x4*>(Ap + 12);
      #pragma unroll
      for (int j = 0; j < 4; j++) {
        int nl = wave * 32 + j * 8 + bl_row;
        const char* gp = (const char*)W1sw + (size_t)(n0 + nl) * 2048
                         + (size_t)k0n * 2 + bl_in;
        gld16(gp, Blds[cur ^ 1] + wave * 4096 + j * 1024);
      }
    }
    // ---- compute on buffers [cur] ----
    #pragma unroll
    for (int kk = 0; kk < 2; kk++) {
      const int kb = kk * 64 + lg * 16;
      bf16x8 a[4], b[4];
      #pragma unroll
      for (int mi = 0; mi < 4; mi++) {
        int row = wr * 64 + mi * 16 + lr;
        a[mi] = *reinterpret_cast<const bf16x8*>(
                    Alds + row * 128 + (kb ^ ((row & 7) << 4)));
      }
      #pragma unroll
      for (int ni = 0; ni < 4; ni++) {
        int nr = wc * 64 + ni * 16 + lr;
        b[ni] = *reinterpret_cast<const bf16x8*>(
                    Blds[cur] + nr * 128 + (kb ^ ((nr & 7) << 4)));
      }
      #pragma unroll
      for (int mi = 0; mi < 4; mi++)
        #pragma unroll
        for (int ni = 0; ni < 4; ni++)
          acc[mi][ni] = __builtin_amdgcn_mfma_f32_16x16x32_bf16(
                            a[mi], b[ni], acc[mi][ni], 0, 0, 0);
    }
    __syncthreads();   // A reads done; vmcnt drain hidden under the 32 MFMAs
    if (pf) {
      bf16x8 w0, w1;
      w0[0]=f2bf(r0[0]); w0[1]=f2bf(r0[1]); w0[2]=f2bf(r0[2]); w0[3]=f2bf(r0[3]);
      w0[4]=f2bf(r1[0]); w0[5]=f2bf(r1[1]); w0[6]=f2bf(r1[2]); w0[7]=f2bf(r1[3]);
      w1[0]=f2bf(r2[0]); w1[1]=f2bf(r2[1]); w1[2]=f2bf(r2[2]); w1[3]=f2bf(r2[3]);
      w1[4]=f2bf(r3[0]); w1[5]=f2bf(r3[1]); w1[6]=f2bf(r3[2]); w1[7]=f2bf(r3[3]);
      int kb = ka * 2;
      *reinterpret_cast<bf16x8*>(Alds + ra * 128 + ( kb       ^ swA)) = w0;
      *reinterpret_cast<bf16x8*>(Alds + ra * 128 + ((kb + 16) ^ swA)) = w1;
    }
    __syncthreads();   // A[t+1] visible; B[t+1] was drained at barrier above
    cur ^= 1;
  }

  // ---- epilogue: partial scores ----
  float* s_sc = (float*)Alds;   // alias A buffer (done with it)
  if (tid < MT) s_sc[tid] = 0.0f;
  __syncthreads();

  float b1v[4], w2v[4];
  #pragma unroll
  for (int ni = 0; ni < 4; ni++) {
    int n = n0 + wc * 64 + ni * 16 + lr;
    b1v[ni] = b1[n];
    w2v[ni] = w2[n];
  }
  #pragma unroll
  for (int mi = 0; mi < 4; mi++) {
    #pragma unroll
    for (int r = 0; r < 4; r++) {
      float p = 0.0f;
      #pragma unroll
      for (int ni = 0; ni < 4; ni++)
        p += fast_tanh(acc[mi][ni][r] + b1v[ni]) * w2v[ni];
      p += __shfl_xor(p, 1);
      p += __shfl_xor(p, 2);
      p += __shfl_xor(p, 4);
      p += __shfl_xor(p, 8);
      if (lr == 0) atomicAdd(&s_sc[wr * 64 + mi * 16 + lg * 4 + r], p);
    }
  }
  __syncthreads();
  if (tid < MT) {
    float* scp = bn ? sc1 : sc0;
    scp[m0 + tid] = s_sc[tid];
  }
}

// ---- kernel 2: sum partials, mask, softmax over s, weights out, weighted sum ----
__global__ void softmax_wsum(const float* __restrict__ src,
                             const float* __restrict__ mask,
                             const float* __restrict__ sc0,
                             const float* __restrict__ sc1,
                             float* __restrict__ out) {
  const int row = blockIdx.x;     // b*TQ+q, 0..799
  const int tid = threadIdx.x;    // 512 threads
  __shared__ float s_e[TS_];

  float v = 0.0f;
  if (tid < TS_) {
    v = (sc0[row * TS_ + tid] + sc1[row * TS_ + tid]) * mask[row * TS_ + tid];
    s_e[tid] = v;
  }
  __syncthreads();
  float mx = -3.0e38f;
  for (int s = 0; s < TS_; s++) mx = fmaxf(mx, s_e[s]);   // LDS broadcast
  __syncthreads();
  if (tid < TS_) s_e[tid] = __expf(v - mx);
  __syncthreads();
  float sum = 0.0f;
  for (int s = 0; s < TS_; s++) sum += s_e[s];
  const float inv = 1.0f / sum;

  float* out_attn = out;                          // [800][512]
  float* out_w    = out + (size_t)B_ * TQ_ * E_;  // [800][100]
  if (tid < TS_) out_w[row * TS_ + tid] = s_e[tid] * inv;

  const float* sp = src + (size_t)row * TS_ * E_ + tid;  // thread owns dim e=tid
  float acc = 0.0f;
  #pragma unroll 4
  for (int s = 0; s < TS_; s++) acc = fmaf(s_e[s], sp[(size_t)s * E_], acc);
  out_attn[row * E_ + tid] = acc * inv;
}

extern "C" void kernel_launch(void* const* d_in, const int* in_sizes, int n_in,
                              void* d_out, int out_size, void* d_ws, size_t ws_size,
                              hipStream_t stream) {
  const float* src  = (const float*)d_in[0];
  const float* tgt  = (const float*)d_in[1];
  const float* mask = (const float*)d_in[2];
  const float* W1   = (const float*)d_in[3];
  const float* b1   = (const float*)d_in[4];
  const float* w2   = (const float*)d_in[5];

  short* W1sw = (short*)d_ws;                                  // 1 MB
  float* sc0  = (float*)((char*)d_ws + (size_t)D_ * K_ * 2);   // 80000 f32
  float* sc1  = sc0 + M_;                                      // 80000 f32

  float* out = (float*)d_out;

  hipLaunchKernelGGL(prep_w1, dim3((K_ * D_) / 256), dim3(256), 0, stream, W1, W1sw);
  hipLaunchKernelGGL(scores_kernel, dim3((M_ / MT) * 2), dim3(NTHREADS), 0, stream,
                     src, tgt, W1sw, b1, w2, sc0, sc1);
  hipLaunchKernelGGL(softmax_wsum, dim3(B_ * TQ_), dim3(512), 0, stream,
                     src, mask, sc0, sc1, out);
}